// Round 5
// baseline (1538.960 us; speedup 1.0000x reference)
//
#include <hip/hip_runtime.h>
#include <hip/hip_bf16.h>

#define H 2
#define C 64
#define IN_CH 64
#define HC (H*C)
#define NEG_SLOPE 0.2f
#define NBUCK_MAX 1024
#define SBLK 512      // scatter blocks (1024 regressed: per-block fixed costs dominate)
#define BKT 64        // nodes per bucket
#define CAP 3072      // per-64-node-bucket capacity (mean ~2046, sigma ~45 -> +23 sigma)

// ================= K1: projection + attention dots (+ cnt zero + graph bounds) =====
__global__ __launch_bounds__(128) void proj_kernel(
    const float* __restrict__ x, const float* __restrict__ W,
    const float* __restrict__ att_src, const float* __restrict__ att_dst,
    const int* __restrict__ batch, __hip_bfloat16* __restrict__ xp,
    float* __restrict__ asrc, float* __restrict__ adst, int* __restrict__ cnt,
    int* __restrict__ gbeg, int N, int nbuck, int G) {
    int t = threadIdx.x;  // output channel 0..127
    if (blockIdx.x == 0)  // zero bucket counters for the (later) scatter dispatch
        for (int i = t; i < nbuck; i += 128) cnt[i] = 0;
    // graph boundary pass over sorted batch: gbeg[g] = first i with batch[i] >= g
    {
        int i = blockIdx.x * 128 + t;
        if (i < N) {
            int bi = batch[i];
            if (i == 0) {
                for (int g = 0; g <= bi; g++) gbeg[g] = 0;
            } else {
                int bp = batch[i - 1];
                for (int g = bp + 1; g <= bi; g++) gbeg[g] = i;
            }
            if (i == N - 1)
                for (int g = bi + 1; g <= G; g++) gbeg[g] = N;
        }
    }
    float w[64];
    const float4* wr = reinterpret_cast<const float4*>(W + (size_t)t * IN_CH);
#pragma unroll
    for (int q = 0; q < 16; q++) {
        float4 v = wr[q];
        w[4 * q] = v.x; w[4 * q + 1] = v.y; w[4 * q + 2] = v.z; w[4 * q + 3] = v.w;
    }
    float a_s = att_src[t], a_d = att_dst[t];
    int lane = t & 63, head = t >> 6;
    for (int n = blockIdx.x; n < N; n += gridDim.x) {
        const float* xr = x + (size_t)n * IN_CH;  // wave-uniform address -> s_load
        float acc = 0.f;
#pragma unroll
        for (int k = 0; k < 64; k++) acc = fmaf(w[k], xr[k], acc);
        xp[(size_t)n * HC + t] = __float2bfloat16(acc);
        float as = acc * a_s, ad = acc * a_d;
#pragma unroll
        for (int d = 32; d > 0; d >>= 1) {
            as += __shfl_xor(as, d, 64);
            ad += __shfl_xor(ad, d, 64);
        }
        if (lane == 0) {
            asrc[(size_t)n * H + head] = as;
            adst[(size_t)n * H + head] = ad;
        }
    }
}

// ================= K2: bucket hist + reservation + scatter (64-node buckets) =======
__global__ __launch_bounds__(256) void scatter_kernel(
    const int* __restrict__ edge, int* __restrict__ cnt,
    int* __restrict__ staged, int N, int E) {
    const int tid = threadIdx.x, bid = blockIdx.x;
    const int nbuck = (N + BKT - 1) / BKT;
    const int chunkE = (E + SBLK - 1) / SBLK;
    const int* srcE = edge;
    const int* dstE = edge + E;
    __shared__ int lh[NBUCK_MAX], bse[NBUCK_MAX], lcur[NBUCK_MAX];
    for (int i = tid; i < nbuck; i += 256) { lh[i] = 0; lcur[i] = 0; }
    __syncthreads();
    int beg = bid * chunkE, end = min(beg + chunkE, E);
    for (int i = beg + tid; i < end; i += 256)
        atomicAdd(&lh[dstE[i] >> 6], 1);
    __syncthreads();
    for (int i = tid; i < nbuck; i += 256)
        bse[i] = atomicAdd(&cnt[i], lh[i]);  // reserve [bse, bse+lh)
    __syncthreads();
    for (int i = beg + tid; i < end; i += 256) {
        int s = srcE[i], d = dstE[i];        // L2-hot re-read
        int b = d >> 6;
        int l = atomicAdd(&lcur[b], 1);
        staged[(size_t)b * CAP + bse[b] + l] = s | ((d & 63) << 20);  // src < 2^20
    }
}

// ================= K3: fused per-bucket softmax + aggregation ======================
// One block per 64-node bucket. LDS f32 accumulators acc[64][128] + den[64][2];
// 4 waves stream the unordered staged edges in 64-edge batches:
//   setup (per lane = per edge): asrc gather, both-head leaky+exp, den atomics,
//   pack (ld<<25 | src<<8) + weight pair into wave-private LDS;
//   accumulate: 16-deep gather pipeline (proven MLP pattern), ds_add_f32 into acc.
// Head-crossed dword interleave on the 2 atomics keeps each instr's 64 lanes on a
// contiguous 64-dword set -> 2 lanes/bank = conflict-free.
// Epilogue: self-loop analytic, normalize, head-mean, bias, write.
__global__ __launch_bounds__(256, 4) void bucketagg_kernel(
    const __hip_bfloat16* __restrict__ xp, const float2* __restrict__ asrc,
    const float2* __restrict__ adst, const int* __restrict__ cnt,
    const int* __restrict__ staged_all, const float* __restrict__ bias,
    float* __restrict__ out, int N) {
    __shared__ float acc[BKT * 128];     // 32KB [node][channel]
    __shared__ float den[BKT * 2];       // [node][head]
    __shared__ float2 adl[BKT];
    __shared__ int   si[4][64];
    __shared__ float2 swv[4][64];
    int b = blockIdx.x;
    int tid = threadIdx.x, lane = tid & 63, wid = tid >> 6;
    int nbase = b * BKT;
    for (int i = tid; i < BKT * 128; i += 256) acc[i] = 0.f;
    if (tid < 2 * BKT) den[tid] = 0.f;
    if (tid < BKT) {
        int n = nbase + tid;
        adl[tid] = (n < N) ? adst[n] : make_float2(0.f, 0.f);
    }
    __syncthreads();
    int size = cnt[b];
    const int* st = staged_all + (size_t)b * CAP;
    const uint* xpw = reinterpret_cast<const uint*>(xp);
    const char* xb = reinterpret_cast<const char*>(xp);
    int hsel = lane >> 5;
    uint laneoff = (uint)lane * 4u;
    float* swl = reinterpret_cast<float*>(&swv[wid][0]) + hsel;
    int* siw = si[wid];

    for (int cb = wid * 64; cb < size; cb += 256) {
        int i = cb + lane;
        if (i < size) {
            int e = st[i];
            int src = e & 0xFFFFF;
            int ld = e >> 20;            // < 64
            float2 as = asrc[src];       // 8B gather; asrc 400KB = L2-resident
            float2 ad = adl[ld];
            float t0 = as.x + ad.x; t0 = fmaxf(t0, NEG_SLOPE * t0);
            float t1 = as.y + ad.y; t1 = fmaxf(t1, NEG_SLOPE * t1);
            float w0 = __expf(t0), w1 = __expf(t1);
            atomicAdd(&den[2 * ld], w0);
            atomicAdd(&den[2 * ld + 1], w1);
            siw[lane] = (ld << 25) | (src << 8);   // src < 2^17
            swv[wid][lane] = make_float2(w0, w1);
        } else {
            siw[lane] = 0;                         // pad: node 0 of bucket, w=0
            swv[wid][lane] = make_float2(0.f, 0.f);
        }
        int nb16 = (min(size - cb, 64) + 15) >> 4;
        for (int q = 0; q < nb16; q++) {
            int jb = q * 16;
            int sv[16];
            uint bu[16];
#pragma unroll
            for (int j = 0; j < 16; j++) sv[j] = siw[jb + j];
#pragma unroll
            for (int j = 0; j < 16; j++) {
                uint boff = ((uint)sv[j] & 0x01FFFF00u) + laneoff;
                bu[j] = *reinterpret_cast<const uint*>(xb + boff);
            }
#pragma unroll
            for (int j = 0; j < 16; j++) {
                float w = swl[2 * (jb + j)];
                uint ld = ((uint)sv[j]) >> 25;
                float m0 = w * __uint_as_float(bu[j] << 16);          // ch 2*lane
                float m1 = w * __uint_as_float(bu[j] & 0xffff0000u);  // ch 2*lane+1
                float* ap = &acc[ld * 128 + 2 * lane];
                // head-crossed order: instr1 covers dwords {2l}(l<32)+{2l+1}(l>=32)
                // = contiguous 64-dword set -> 2/bank (free); same for instr2.
                atomicAdd(ap + hsel, hsel ? m1 : m0);
                atomicAdd(ap + (hsel ^ 1), hsel ? m0 : m1);
            }
        }
    }
    __syncthreads();
    // epilogue: 16 nodes per wave
    for (int k = 0; k < 16; k++) {
        int nd = wid * 16 + k;
        int n = nbase + nd;
        if (n >= N) break;
        uint u = xpw[(size_t)n * 64 + lane];
        float2 asn = asrc[n];
        float2 ad2 = adl[nd];
        float t = hsel ? (asn.y + ad2.y) : (asn.x + ad2.x);
        t = fmaxf(t, NEG_SLOPE * t);
        float ws = __expf(t);
        float dh = den[2 * nd + hsel] + ws;
        float a0 = acc[nd * 128 + 2 * lane]     + ws * __uint_as_float(u << 16);
        float a1 = acc[nd * 128 + 2 * lane + 1] + ws * __uint_as_float(u & 0xffff0000u);
        float inv = 1.f / dh;
        a0 *= inv; a1 *= inv;
        float ox = 0.5f * (a0 + __shfl_xor(a0, 32, 64));
        float oy = 0.5f * (a1 + __shfl_xor(a1, 32, 64));
        if (lane < 32) {
            float vx = ox + bias[2 * lane];
            float vy = oy + bias[2 * lane + 1];
            *reinterpret_cast<float2*>(out + (size_t)n * C + 2 * lane) =
                make_float2(vx, vy);
        }
    }
}

// ================= K4: pool = segment mean via precomputed bounds, 4 row-streams ====
__global__ __launch_bounds__(256) void pool_kernel(const float* __restrict__ hn,
                                                   const int* __restrict__ gbeg,
                                                   float* __restrict__ outG, int G) {
    int g = blockIdx.x;
    int c = threadIdx.x & 63, r = threadIdx.x >> 6;  // 4 parallel row streams
    int beg = gbeg[g], end = gbeg[g + 1];
    float s = 0.f;
    for (int n = beg + r; n < end; n += 4) s += hn[(size_t)n * C + c];
    __shared__ float red[256];
    red[threadIdx.x] = s;
    __syncthreads();
    if (r == 0) {
        float tot = red[c] + red[64 + c] + red[128 + c] + red[192 + c];
        outG[(size_t)g * C + c] = tot / fmaxf((float)(end - beg), 1.f);
    }
}

extern "C" void kernel_launch(void* const* d_in, const int* in_sizes, int n_in,
                              void* d_out, int out_size, void* d_ws, size_t ws_size,
                              hipStream_t stream) {
    const float* x       = (const float*)d_in[0];
    const int*   edge    = (const int*)d_in[1];
    const int*   batch   = (const int*)d_in[2];
    const float* W       = (const float*)d_in[3];
    const float* att_src = (const float*)d_in[4];
    const float* att_dst = (const float*)d_in[5];
    const float* bias    = (const float*)d_in[6];

    int N = in_sizes[0] / IN_CH;
    int E = in_sizes[1] / 2;
    int G = out_size / C - N;
    int nbuck = (N + BKT - 1) / BKT;       // 782 for N=50000 (must be <= 1024)

    char* p = (char*)d_ws;
    auto alloc = [&](size_t bytes) {
        char* r = p;
        p += (bytes + 255) & ~(size_t)255;
        return r;
    };
    __hip_bfloat16* xp = (__hip_bfloat16*)alloc((size_t)N * HC * 2);
    float* asrc    = (float*)alloc((size_t)N * H * 4);
    float* adst    = (float*)alloc((size_t)N * H * 4);
    int*   cnt     = (int*)alloc((size_t)nbuck * 4);
    int*   staged  = (int*)alloc((size_t)nbuck * CAP * 4);
    int*   gbeg    = (int*)alloc((size_t)(G + 1) * 4);

    proj_kernel<<<2048, 128, 0, stream>>>(x, W, att_src, att_dst, batch, xp, asrc, adst,
                                          cnt, gbeg, N, nbuck, G);
    scatter_kernel<<<SBLK, 256, 0, stream>>>(edge, cnt, staged, N, E);
    bucketagg_kernel<<<nbuck, 256, 0, stream>>>(xp, (const float2*)asrc,
                                                (const float2*)adst, cnt, staged, bias,
                                                (float*)d_out, N);
    pool_kernel<<<G, 256, 0, stream>>>((const float*)d_out, gbeg,
                                       (float*)d_out + (size_t)N * C, G);
}

// Round 6
// 199.840 us; speedup vs baseline: 7.7010x; 7.7010x over previous
//
#include <hip/hip_runtime.h>
#include <hip/hip_bf16.h>

#define H 2
#define C 64
#define IN_CH 64
#define HC (H*C)
#define NEG_SLOPE 0.2f
#define NBUCK_MAX 512
#define SBLK 512      // scatter/hist chunks
#define CAP 6144      // per-128-node-bucket staging capacity (mean ~4092, sigma ~64)

// ================= K1: fused {per-chunk bucket histogram} || {projection + att dots}
// Blocks [0,SBLK): histogram role -- count bucket occupancy of this block's edge
// chunk into hist[block][bucket] with plain writes (NO global atomics; the round-4
// scatter reserved ranges via 391x512 same-address cross-XCD atomic chains, ~26-66us).
// Blocks [SBLK, SBLK+2048): proj role (unchanged round-4 logic) + gbeg bounds.
__global__ __launch_bounds__(128) void proj_hist_kernel(
    const float* __restrict__ x, const float* __restrict__ W,
    const float* __restrict__ att_src, const float* __restrict__ att_dst,
    const int* __restrict__ batch, const int* __restrict__ edge,
    __hip_bfloat16* __restrict__ xp,
    float* __restrict__ asrc, float* __restrict__ adst, int* __restrict__ hist,
    int* __restrict__ gbeg, int N, int E, int G, int nbuck) {
    int t = threadIdx.x;
    if (blockIdx.x < SBLK) {   // -------- histogram role --------
        __shared__ int lh[NBUCK_MAX];
        for (int i = t; i < nbuck; i += 128) lh[i] = 0;
        __syncthreads();
        const int* dstE = edge + E;
        int chunkE = (E + SBLK - 1) / SBLK;
        int beg = blockIdx.x * chunkE, end = min(beg + chunkE, E);
        for (int i = beg + t; i < end; i += 128)
            atomicAdd(&lh[dstE[i] >> 7], 1);
        __syncthreads();
        for (int i = t; i < nbuck; i += 128)
            hist[(size_t)blockIdx.x * nbuck + i] = lh[i];
        return;
    }
    int pb = blockIdx.x - SBLK;        // proj-role block id, 0..2047
    int gridP = gridDim.x - SBLK;
    // graph boundary pass over sorted batch: gbeg[g] = first i with batch[i] >= g
    {
        int i = pb * 128 + t;
        if (i < N) {
            int bi = batch[i];
            if (i == 0) {
                for (int g = 0; g <= bi; g++) gbeg[g] = 0;
            } else {
                int bp = batch[i - 1];
                for (int g = bp + 1; g <= bi; g++) gbeg[g] = i;
            }
            if (i == N - 1)
                for (int g = bi + 1; g <= G; g++) gbeg[g] = N;
        }
    }
    float w[64];
    const float4* wr = reinterpret_cast<const float4*>(W + (size_t)t * IN_CH);
#pragma unroll
    for (int q = 0; q < 16; q++) {
        float4 v = wr[q];
        w[4 * q] = v.x; w[4 * q + 1] = v.y; w[4 * q + 2] = v.z; w[4 * q + 3] = v.w;
    }
    float a_s = att_src[t], a_d = att_dst[t];
    int lane = t & 63, head = t >> 6;
    for (int n = pb; n < N; n += gridP) {
        const float* xr = x + (size_t)n * IN_CH;  // wave-uniform address -> s_load
        float acc = 0.f;
#pragma unroll
        for (int k = 0; k < 64; k++) acc = fmaf(w[k], xr[k], acc);
        xp[(size_t)n * HC + t] = __float2bfloat16(acc);
        float as = acc * a_s, ad = acc * a_d;
#pragma unroll
        for (int d = 32; d > 0; d >>= 1) {
            as += __shfl_xor(as, d, 64);
            ad += __shfl_xor(ad, d, 64);
        }
        if (lane == 0) {
            asrc[(size_t)n * H + head] = as;
            adst[(size_t)n * H + head] = ad;
        }
    }
}

// ================= K2: per-bucket exclusive prefix over the 512 chunk histograms ===
// bse_t[bucket][block] = sum of hist[block'<block][bucket]; cnt[bucket] = total.
// Exact, deterministic, atomic-free replacement for the reservation chains.
__global__ __launch_bounds__(512) void prefix_kernel(const int* __restrict__ hist,
                                                     int* __restrict__ bse_t,
                                                     int* __restrict__ cnt, int nbuck) {
    int b = blockIdx.x;   // bucket
    int t = threadIdx.x;  // chunk/block index
    __shared__ int sh[512];
    int v = hist[(size_t)t * nbuck + b];
    sh[t] = v;
    __syncthreads();
    for (int d = 1; d < 512; d <<= 1) {
        int u = (t >= d) ? sh[t - d] : 0;
        __syncthreads();
        sh[t] += u;
        __syncthreads();
    }
    bse_t[(size_t)b * SBLK + t] = sh[t] - v;   // exclusive; coalesced write
    if (t == 511) cnt[b] = sh[511];
}

// ================= K3: scatter into reserved (deterministic) bucket windows ========
__global__ __launch_bounds__(256) void scatter_kernel(
    const int* __restrict__ edge, const int* __restrict__ bse_t,
    int* __restrict__ staged, int N, int E) {
    const int tid = threadIdx.x, bid = blockIdx.x;
    const int nbuck = (N + 127) >> 7;
    const int chunkE = (E + SBLK - 1) / SBLK;
    const int* srcE = edge;
    const int* dstE = edge + E;
    __shared__ int sbase[NBUCK_MAX], lcur[NBUCK_MAX];
    for (int i = tid; i < nbuck; i += 256) {
        sbase[i] = bse_t[(size_t)i * SBLK + bid];  // own column, L2-hot
        lcur[i] = 0;
    }
    __syncthreads();
    int beg = bid * chunkE, end = min(beg + chunkE, E);
    for (int i = beg + tid; i < end; i += 256) {
        int s = srcE[i], d = dstE[i];
        int b = d >> 7;
        int l = atomicAdd(&lcur[b], 1);
        staged[(size_t)b * CAP + sbase[b] + l] = s | ((d & 127) << 20);  // src < 2^20
    }
}

// ================= K4: per-bucket CSR finalize (nbuck blocks x 512 thr) ============
__global__ __launch_bounds__(512) void bucket_csr_kernel(
    const int* __restrict__ staged, const int* __restrict__ cnt,
    int* __restrict__ off, int* __restrict__ csr, int N, int nbuck) {
    int b = blockIdx.x, t = threadIdx.x;
    __shared__ int bse[512], rs[512], lh[128], sh[128], cur[128];
    {   // exclusive scan of cnt[nbuck] -> bse (512-wide)
        int v = (t < nbuck) ? cnt[t] : 0;
        bse[t] = v; rs[t] = v;
        __syncthreads();
        for (int d = 1; d < 512; d <<= 1) {
            int u = (t >= d) ? bse[t - d] : 0;
            __syncthreads();
            bse[t] += u;
            __syncthreads();
        }
        bse[t] -= rs[t];
        __syncthreads();
    }
    int base = bse[b], size = rs[b];
    const int* st = staged + (size_t)b * CAP;
    if (t < 128) lh[t] = 0;
    __syncthreads();
    for (int i = t; i < size; i += 512)
        atomicAdd(&lh[st[i] >> 20], 1);
    __syncthreads();
    int v = (t < 128) ? lh[t] : 0;
    if (t < 128) sh[t] = v;
    __syncthreads();
    for (int d = 1; d < 128; d <<= 1) {
        int u = (t >= d && t < 128) ? sh[t - d] : 0;
        __syncthreads();
        if (t < 128) sh[t] += u;
        __syncthreads();
    }
    if (t < 128) {
        int ex = sh[t] - v;
        int nd = b * 128 + t;
        if (nd < N) off[nd] = base + ex;
        if (nd == N - 1) off[N] = base + size;
        cur[t] = base + ex;
    }
    __syncthreads();
    for (int i = t; i < size; i += 512) {
        int e = st[i];
        int pos = atomicAdd(&cur[e >> 20], 1);
        csr[pos] = e & 0xFFFFF;
    }
}

// -------- gather+FMA over NB staged edges: byte offsets pre-staged (idx<<8), head
// weight fetched with a single ds_read at imm offset 2*j (swl already +hsel). All
// loads issued before any FMA for max MLP.
template<int NB>
__device__ __forceinline__ void gfma(const uint* __restrict__ xpw,
                                     const int* __restrict__ si,
                                     const float* __restrict__ swl,
                                     uint laneoff, float& accx, float& accy) {
    const char* xb = reinterpret_cast<const char*>(xpw);
    uint bu[NB];
#pragma unroll
    for (int j = 0; j < NB; j++) {
        uint boff = (uint)si[j] + laneoff;           // idx*256 + lane*4
        bu[j] = *reinterpret_cast<const uint*>(xb + boff);
    }
#pragma unroll
    for (int j = 0; j < NB; j++) {
        float w = swl[2 * j];                        // swf[2*j + hsel]
        accx = fmaf(w, __uint_as_float(bu[j] << 16), accx);
        accy = fmaf(w, __uint_as_float(bu[j] & 0xffff0000u), accy);
    }
}

// ================= K5: softmax + aggregation (one wave per dst node) ================
// Head-split lanes: lanes 0-31 own head 0, lanes 32-63 own head 1.
// (256,4): DO NOT raise the min-waves bound -- (256,8) forced VGPR 40->32 and the
// gather buffer spilled to scratch (+50MB WRITE_SIZE, 51.7->64.2us). MLP > occupancy.
// Register accumulation only: LDS-atomic accumulation measured ~1 lane-op/cyc/CU
// (round-5 bucketagg: 1404us, VALUBusy 2.6%).
__global__ __launch_bounds__(256, 4) void aggregate_kernel(
    const __hip_bfloat16* __restrict__ xp, const float* __restrict__ asrc,
    const float* __restrict__ adst, const int* __restrict__ off,
    const int* __restrict__ csr, const float* __restrict__ bias,
    float* __restrict__ out, int N) {
    __shared__ int sidx[4][32];
    __shared__ float swf[4][64];
    int wid = threadIdx.x >> 6;
    int n = blockIdx.x * 4 + wid;
    if (n >= N) return;
    int lane = threadIdx.x & 63;
    int cl = lane & 31;          // edge slot within the 32-batch
    int hsel = lane >> 5;        // head this lane owns
    int* si = sidx[wid];
    float* swl = swf[wid] + hsel;
    int o0 = off[n];
    int deg = off[n + 1] - o0;   // real edges only (self-loop analytic)
    float adh = adst[2 * n + hsel];
    float es = asrc[2 * n + hsel] + adh;
    es = (es > 0.f) ? es : NEG_SLOPE * es;
    float wself = __expf(es);
    // self-loop weight enters the denominator exactly once per head (cl==0 lane):
    float ssum = (cl == 0) ? wself : 0.f;

    const uint* xpw = reinterpret_cast<const uint*>(xp);
    uint laneoff = (uint)lane * 4u;   // lanes<32 -> head0 channels, >=32 -> head1
    float accx, accy;
    {   // self-loop contribution
        uint u = xpw[(size_t)n * 64 + lane];
        accx = wself * __uint_as_float(u << 16);
        accy = wself * __uint_as_float(u & 0xffff0000u);
    }

    for (int base = 0; base < deg; base += 32) {
        int i = base + cl;
        int idx = 0;
        float w = 0.f;
        if (i < deg) {
            idx = csr[o0 + i];   // both halves load same 32 -> coalesced/broadcast
            float t = asrc[2 * idx + hsel] + adh;
            t = (t > 0.f) ? t : NEG_SLOPE * t;
            w = __expf(t);
        }
        ssum += w;
        if (!hsel) si[cl] = idx << 8;  // one writer per slot (both halves hold same idx)
        swl[2 * cl] = w;               // swf[2*cl + hsel]; 2-way bank alias = free
        int nb = min(deg - base, 32);
        if (nb > 16) gfma<32>(xpw, si, swl, laneoff, accx, accy);
        else         gfma<16>(xpw, si, swl, laneoff, accx, accy);
    }
    // per-head denominator: xor distances <=16 stay within each 32-lane half
#pragma unroll
    for (int d = 16; d > 0; d >>= 1) ssum += __shfl_xor(ssum, d, 64);
    float inv = 1.f / ssum;
    accx *= inv;
    accy *= inv;
    // head mean: lane l and l+32 hold the same output channel of the two heads
    float ox = 0.5f * (accx + __shfl_xor(accx, 32, 64));
    float oy = 0.5f * (accy + __shfl_xor(accy, 32, 64));
    if (lane < 32) {
        float vx = ox + bias[2 * cl];
        float vy = oy + bias[2 * cl + 1];
        *reinterpret_cast<float2*>(out + (size_t)n * C + 2 * cl) = make_float2(vx, vy);
    }
}

// ================= K6: pool = segment mean via precomputed bounds, 4 row-streams ====
__global__ __launch_bounds__(256) void pool_kernel(const float* __restrict__ hn,
                                                   const int* __restrict__ gbeg,
                                                   float* __restrict__ outG, int G) {
    int g = blockIdx.x;
    int c = threadIdx.x & 63, r = threadIdx.x >> 6;  // 4 parallel row streams
    int beg = gbeg[g], end = gbeg[g + 1];
    float s = 0.f;
    for (int n = beg + r; n < end; n += 4) s += hn[(size_t)n * C + c];
    __shared__ float red[256];
    red[threadIdx.x] = s;
    __syncthreads();
    if (r == 0) {
        float tot = red[c] + red[64 + c] + red[128 + c] + red[192 + c];
        outG[(size_t)g * C + c] = tot / fmaxf((float)(end - beg), 1.f);
    }
}

extern "C" void kernel_launch(void* const* d_in, const int* in_sizes, int n_in,
                              void* d_out, int out_size, void* d_ws, size_t ws_size,
                              hipStream_t stream) {
    const float* x       = (const float*)d_in[0];
    const int*   edge    = (const int*)d_in[1];
    const int*   batch   = (const int*)d_in[2];
    const float* W       = (const float*)d_in[3];
    const float* att_src = (const float*)d_in[4];
    const float* att_dst = (const float*)d_in[5];
    const float* bias    = (const float*)d_in[6];

    int N = in_sizes[0] / IN_CH;
    int E = in_sizes[1] / 2;
    int G = out_size / C - N;
    int nbuck = (N + 127) >> 7;            // 391 for N=50000 (must be <= 512)

    char* p = (char*)d_ws;
    auto alloc = [&](size_t bytes) {
        char* r = p;
        p += (bytes + 255) & ~(size_t)255;
        return r;
    };
    __hip_bfloat16* xp = (__hip_bfloat16*)alloc((size_t)N * HC * 2);
    float* asrc    = (float*)alloc((size_t)N * H * 4);
    float* adst    = (float*)alloc((size_t)N * H * 4);
    int*   hist    = (int*)alloc((size_t)SBLK * nbuck * 4);
    int*   bse_t   = (int*)alloc((size_t)nbuck * SBLK * 4);
    int*   cnt     = (int*)alloc((size_t)nbuck * 4);
    int*   off     = (int*)alloc((size_t)(N + 1) * 4);
    int*   staged  = (int*)alloc((size_t)nbuck * CAP * 4);
    int*   csr     = (int*)alloc((size_t)E * 4);
    int*   gbeg    = (int*)alloc((size_t)(G + 1) * 4);

    proj_hist_kernel<<<SBLK + 2048, 128, 0, stream>>>(x, W, att_src, att_dst, batch,
                                                      edge, xp, asrc, adst, hist, gbeg,
                                                      N, E, G, nbuck);
    prefix_kernel<<<nbuck, 512, 0, stream>>>(hist, bse_t, cnt, nbuck);
    scatter_kernel<<<SBLK, 256, 0, stream>>>(edge, bse_t, staged, N, E);
    bucket_csr_kernel<<<nbuck, 512, 0, stream>>>(staged, cnt, off, csr, N, nbuck);
    aggregate_kernel<<<(N + 3) / 4, 256, 0, stream>>>(xp, asrc, adst, off, csr, bias,
                                                      (float*)d_out, N);
    pool_kernel<<<G, 256, 0, stream>>>((const float*)d_out, gbeg,
                                       (float*)d_out + (size_t)N * C, G);
}